// Round 3
// baseline (1430.646 us; speedup 1.0000x reference)
//
#include <hip/hip_runtime.h>
#include <math.h>

#define NN 100000
#define NE 1600000
#define F_IN 64
#define HID 16
#define OUTF 32
#define BKT_SHIFT 6
#define BKT_NODES 64
#define NBKT ((NN + BKT_NODES - 1) / BKT_NODES)   // 1563

// ---------------- bucket histogram ----------------
__global__ __launch_bounds__(256) void histb_kernel(const int* __restrict__ ei,
                                                    int* __restrict__ bcnt) {
    int e = blockIdx.x * 256 + threadIdx.x;
    if (e >= NE) return;
    atomicAdd(&bcnt[ei[NE + e] >> BKT_SHIFT], 1);
}

// ---------------- single-block exclusive scan over NBKT buckets ----------------
__global__ __launch_bounds__(256) void bscan_kernel(const int* __restrict__ bcnt,
                                                    int* __restrict__ bbase) {
    __shared__ int s[256];
    const int PER = (NBKT + 255) / 256;  // 7
    int t = threadIdx.x;
    int base = t * PER;
    int vals[8];
    int loc = 0;
    for (int i = 0; i < PER; ++i) {
        int idx = base + i;
        int v = (idx < NBKT) ? bcnt[idx] : 0;
        vals[i] = loc;
        loc += v;
    }
    s[t] = loc;
    __syncthreads();
    for (int off = 1; off < 256; off <<= 1) {
        int xv = (t >= off) ? s[t - off] : 0;
        __syncthreads();
        s[t] += xv;
        __syncthreads();
    }
    int pre = (t == 0) ? 0 : s[t - 1];
    for (int i = 0; i < PER; ++i) {
        int idx = base + i;
        if (idx < NBKT) bbase[idx] = pre + vals[i];
    }
    if (t == 255) bbase[NBKT] = NE;
}

// ---------------- partition edges into buckets; pack (src|loc<<17, u) ----------------
__global__ __launch_bounds__(256) void partition_kernel(const int* __restrict__ ei,
                                                        const float* __restrict__ ea,
                                                        const int* __restrict__ bbase,
                                                        int* __restrict__ bcur,
                                                        int2* __restrict__ bkt) {
    int e = blockIdx.x * 256 + threadIdx.x;
    if (e >= NE) return;
    int src = ei[e];
    int dst = ei[NE + e];
    float u = ea[e];
    int b = dst >> BKT_SHIFT;
    int p = bbase[b] + atomicAdd(&bcur[b], 1);
    bkt[p] = make_int2(src | ((dst & (BKT_NODES - 1)) << 17), __float_as_int(u));
}

// ---------------- layer-1 projection: ab1[n][j] = (a, b-a) ----------------
__global__ __launch_bounds__(256) void proj1_kernel(const float* __restrict__ x,
                                                    const float* __restrict__ W1,
                                                    float2* __restrict__ ab1) {
    __shared__ float w[2 * F_IN * HID];
    for (int i = threadIdx.x; i < 2 * F_IN * HID; i += 256) w[i] = W1[i];
    __syncthreads();
    int n = blockIdx.x * 256 + threadIdx.x;
    if (n >= NN) return;
    float accA[HID], accB[HID];
#pragma unroll
    for (int o = 0; o < HID; ++o) { accA[o] = 0.f; accB[o] = 0.f; }
    const float* xr = x + (size_t)n * F_IN;
    for (int f = 0; f < F_IN; ++f) {
        float xv = xr[f];
        const float* w0 = &w[f * HID];
        const float* w1 = &w[F_IN * HID + f * HID];
#pragma unroll
        for (int o = 0; o < HID; ++o) {
            accA[o] = fmaf(xv, w0[o], accA[o]);
            accB[o] = fmaf(xv, w1[o], accB[o]);
        }
    }
    float2* ar = ab1 + (size_t)n * HID;
#pragma unroll
    for (int o = 0; o < HID; ++o) ar[o] = make_float2(accA[o], accB[o] - accA[o]);
}

// ---------------- layer-1 bucketed gather + mean + root + bias + ELU -> h ----------------
__global__ __launch_bounds__(256) void gather1_kernel(const int* __restrict__ bbase,
                                                      const int2* __restrict__ bkt,
                                                      const float2* __restrict__ ab1,
                                                      const float* __restrict__ x,
                                                      const float* __restrict__ root1,
                                                      const float* __restrict__ bias1,
                                                      float* __restrict__ h) {
    __shared__ float acc[BKT_NODES * HID];  // 1024
    __shared__ float degs[BKT_NODES];
    __shared__ float w[F_IN * HID];         // 1024
    __shared__ float bb[HID];
    int t = threadIdx.x;
    for (int i = t; i < F_IN * HID; i += 256) w[i] = root1[i];
    if (t < HID) bb[t] = bias1[t];
    for (int i = t; i < BKT_NODES * HID; i += 256) acc[i] = 0.f;
    if (t < BKT_NODES) degs[t] = 0.f;
    __syncthreads();
    int b = blockIdx.x;
    int beg = bbase[b], end = bbase[b + 1];
    int j = t & (HID - 1);
    int g = t >> 4;  // 16 groups
    for (int e = beg + g; e < end; e += 16) {
        int2 pk = bkt[e];
        int src = pk.x & 0x1FFFF;
        int loc = pk.x >> 17;
        float u = __int_as_float(pk.y);
        float2 ab = ab1[(size_t)src * HID + j];
        atomicAdd(&acc[loc * HID + j], fmaf(u, ab.y, ab.x));
        if (j == 0) atomicAdd(&degs[loc], 1.f);
    }
    __syncthreads();
    int nodeBase = b * BKT_NODES;
#pragma unroll
    for (int it = 0; it < BKT_NODES * HID / 256; ++it) {  // 4
        int idx = it * 256 + t;
        int nl = idx >> 4, jj = idx & (HID - 1);
        int n = nodeBase + nl;
        if (n < NN) {
            float v = acc[idx] / fmaxf(degs[nl], 1.f) + bb[jj];
            const float* xr = x + (size_t)n * F_IN;
#pragma unroll
            for (int f = 0; f < F_IN; ++f) v = fmaf(xr[f], w[f * HID + jj], v);
            h[(size_t)n * HID + jj] = v > 0.f ? v : expm1f(v);
        }
    }
}

// ---------------- layer-2 projection ----------------
__global__ __launch_bounds__(256) void proj2_kernel(const float* __restrict__ h,
                                                    const float* __restrict__ W2,
                                                    float2* __restrict__ ab2) {
    __shared__ float w[2 * HID * OUTF];
    for (int i = threadIdx.x; i < 2 * HID * OUTF; i += 256) w[i] = W2[i];
    __syncthreads();
    int n = blockIdx.x * 256 + threadIdx.x;
    if (n >= NN) return;
    float accA[OUTF], accB[OUTF];
#pragma unroll
    for (int o = 0; o < OUTF; ++o) { accA[o] = 0.f; accB[o] = 0.f; }
    const float* hr = h + (size_t)n * HID;
#pragma unroll
    for (int f = 0; f < HID; ++f) {
        float hv = hr[f];
        const float* w0 = &w[f * OUTF];
        const float* w1 = &w[HID * OUTF + f * OUTF];
#pragma unroll
        for (int o = 0; o < OUTF; ++o) {
            accA[o] = fmaf(hv, w0[o], accA[o]);
            accB[o] = fmaf(hv, w1[o], accB[o]);
        }
    }
    float2* ar = ab2 + (size_t)n * OUTF;
#pragma unroll
    for (int o = 0; o < OUTF; ++o) ar[o] = make_float2(accA[o], accB[o] - accA[o]);
}

// ---------------- layer-2 bucketed gather + mean + root + bias + log_softmax -> out ----------------
__global__ __launch_bounds__(256) void gather2_kernel(const int* __restrict__ bbase,
                                                      const int2* __restrict__ bkt,
                                                      const float2* __restrict__ ab2,
                                                      const float* __restrict__ h,
                                                      const float* __restrict__ root2,
                                                      const float* __restrict__ bias2,
                                                      float* __restrict__ out) {
    __shared__ float acc[BKT_NODES * OUTF];  // 2048
    __shared__ float degs[BKT_NODES];
    __shared__ float w[HID * OUTF];          // 512
    __shared__ float bb[OUTF];
    int t = threadIdx.x;
    for (int i = t; i < HID * OUTF; i += 256) w[i] = root2[i];
    if (t < OUTF) bb[t] = bias2[t];
    for (int i = t; i < BKT_NODES * OUTF; i += 256) acc[i] = 0.f;
    if (t < BKT_NODES) degs[t] = 0.f;
    __syncthreads();
    int b = blockIdx.x;
    int beg = bbase[b], end = bbase[b + 1];
    int j = t & (OUTF - 1);
    int g = t >> 5;  // 8 groups
    for (int e = beg + g; e < end; e += 8) {
        int2 pk = bkt[e];
        int src = pk.x & 0x1FFFF;
        int loc = pk.x >> 17;
        float u = __int_as_float(pk.y);
        float2 ab = ab2[(size_t)src * OUTF + j];
        atomicAdd(&acc[loc * OUTF + j], fmaf(u, ab.y, ab.x));
        if (j == 0) atomicAdd(&degs[loc], 1.f);
    }
    __syncthreads();
    int nodeBase = b * BKT_NODES;
#pragma unroll
    for (int it = 0; it < BKT_NODES * OUTF / 256; ++it) {  // 8
        int idx = it * 256 + t;
        int nl = idx >> 5, jj = idx & (OUTF - 1);
        int n = nodeBase + nl;
        float v = 0.f;
        if (n < NN) {
            v = acc[idx] / fmaxf(degs[nl], 1.f) + bb[jj];
            const float* hr = h + (size_t)n * HID;
#pragma unroll
            for (int f = 0; f < HID; ++f) v = fmaf(hr[f], w[f * OUTF + jj], v);
        }
        // log_softmax over the 32 consecutive lanes sharing this node
        float m = v;
#pragma unroll
        for (int mask = 16; mask >= 1; mask >>= 1) m = fmaxf(m, __shfl_xor(m, mask));
        float ex = expf(v - m);
        float s = ex;
#pragma unroll
        for (int mask = 16; mask >= 1; mask >>= 1) s += __shfl_xor(s, mask);
        if (n < NN) out[(size_t)n * OUTF + jj] = v - m - logf(s);
    }
}

extern "C" void kernel_launch(void* const* d_in, const int* in_sizes, int n_in,
                              void* d_out, int out_size, void* d_ws, size_t ws_size,
                              hipStream_t stream) {
    const float* x     = (const float*)d_in[0];
    const int*   ei    = (const int*)d_in[1];
    const float* ea    = (const float*)d_in[3];
    const float* W1    = (const float*)d_in[4];
    const float* root1 = (const float*)d_in[5];
    const float* bias1 = (const float*)d_in[6];
    const float* W2    = (const float*)d_in[7];
    const float* root2 = (const float*)d_in[8];
    const float* bias2 = (const float*)d_in[9];
    float* out = (float*)d_out;
    float* ws  = (float*)d_ws;

    const size_t N = NN;
    // workspace layout (float units): header 8192 + h 16N + bkt 32N + ab 64N = 112N + 8192
    int*    bcnt  = (int*)(ws);                  // [0, NBKT)
    int*    bcur  = (int*)(ws + NBKT);           // [NBKT, 2*NBKT)
    int*    bbase = (int*)(ws + 2 * NBKT);       // [2*NBKT, 3*NBKT+1)
    float*  h     = ws + 8192;                   // 16N floats
    int2*   bkt   = (int2*)(ws + 8192 + 16 * N); // E int2 = 32N floats
    float2* ab1   = (float2*)(ws + 8192 + 48 * N);
    float2* ab2   = (float2*)(ws + 8192 + 48 * N);  // reuses ab1 space (sequential)

    hipMemsetAsync(bcnt, 0, NBKT * sizeof(int), stream);
    hipMemsetAsync(bcur, 0, NBKT * sizeof(int), stream);

    int nbE = (NE + 255) / 256;
    int nbN = (NN + 255) / 256;
    histb_kernel<<<nbE, 256, 0, stream>>>(ei, bcnt);
    bscan_kernel<<<1, 256, 0, stream>>>(bcnt, bbase);
    partition_kernel<<<nbE, 256, 0, stream>>>(ei, ea, bbase, bcur, bkt);

    proj1_kernel<<<nbN, 256, 0, stream>>>(x, W1, ab1);
    gather1_kernel<<<NBKT, 256, 0, stream>>>(bbase, bkt, ab1, x, root1, bias1, h);
    proj2_kernel<<<nbN, 256, 0, stream>>>(h, W2, ab2);
    gather2_kernel<<<NBKT, 256, 0, stream>>>(bbase, bkt, ab2, h, root2, bias2, out);
}

// Round 4
// 773.737 us; speedup vs baseline: 1.8490x; 1.8490x over previous
//
#include <hip/hip_runtime.h>
#include <math.h>

#define NN 100000
#define NE 1600000
#define F_IN 64
#define HID 16
#define OUTF 32
#define BKT_SHIFT 6
#define BKT_NODES 64
#define NBKT 1563               // ceil(NN/64)
#define PBLK 64                 // partition blocks
#define EPB (NE / PBLK)         // 25000 edges per partition block
#define M_HIST (NBKT * PBLK)    // 100032

// ---------------- A: per-block bucket histogram (LDS atomics only) ----------------
__global__ __launch_bounds__(256) void histA_kernel(const int* __restrict__ ei,
                                                    int* __restrict__ hist) {
    __shared__ int hcnt[NBKT];
    int t = threadIdx.x, blk = blockIdx.x;
    for (int i = t; i < NBKT; i += 256) hcnt[i] = 0;
    __syncthreads();
    int beg = blk * EPB, end = beg + EPB;
    for (int e = beg + t; e < end; e += 256)
        atomicAdd(&hcnt[ei[NE + e] >> BKT_SHIFT], 1);
    __syncthreads();
    for (int i = t; i < NBKT; i += 256) hist[i * PBLK + blk] = hcnt[i];
}

// ---------------- B: exclusive scan over [bkt][blk] matrix (one block) ----------------
__global__ __launch_bounds__(1024) void scanB_kernel(const int* __restrict__ hist,
                                                     int* __restrict__ base,
                                                     int* __restrict__ bbase) {
    __shared__ int s[1024];
    int t = threadIdx.x;
    const int PER = (M_HIST + 1023) / 1024;  // 98
    int lo = t * PER;
    int hi = lo + PER; if (hi > M_HIST) hi = M_HIST;
    int sum = 0;
    for (int i = lo; i < hi; ++i) sum += hist[i];
    s[t] = sum;
    __syncthreads();
    for (int off = 1; off < 1024; off <<= 1) {
        int xv = (t >= off) ? s[t - off] : 0;
        __syncthreads();
        s[t] += xv;
        __syncthreads();
    }
    int run = (t == 0) ? 0 : s[t - 1];
    for (int i = lo; i < hi; ++i) {
        base[i] = run;
        if ((i & (PBLK - 1)) == 0) bbase[i / PBLK] = run;
        run += hist[i];
    }
    if (t == 1023) bbase[NBKT] = NE;
}

// ---------------- C: partition edges (LDS cursors, no global atomics) ----------------
__global__ __launch_bounds__(256) void scatterC_kernel(const int* __restrict__ ei,
                                                       const float* __restrict__ ea,
                                                       const int* __restrict__ base,
                                                       int2* __restrict__ bkt) {
    __shared__ int cur[NBKT];
    int t = threadIdx.x, blk = blockIdx.x;
    for (int i = t; i < NBKT; i += 256) cur[i] = base[i * PBLK + blk];
    __syncthreads();
    int beg = blk * EPB, end = beg + EPB;
    for (int e = beg + t; e < end; e += 256) {
        int src = ei[e];
        int dst = ei[NE + e];
        float u = ea[e];
        int b = dst >> BKT_SHIFT;
        int p = atomicAdd(&cur[b], 1);
        bkt[p] = make_int2(src | ((dst & (BKT_NODES - 1)) << 17), __float_as_int(u));
    }
}

// ---------------- layer-1 projection: ab1 = (a, b-a); r1 = x@root1 + bias1 ----------------
__global__ __launch_bounds__(256) void proj1_kernel(const float* __restrict__ x,
                                                    const float* __restrict__ W1,
                                                    const float* __restrict__ root1,
                                                    const float* __restrict__ bias1,
                                                    float2* __restrict__ ab1,
                                                    float* __restrict__ r1) {
    __shared__ float w[2 * F_IN * HID];  // 2048
    __shared__ float wr[F_IN * HID];     // 1024
    __shared__ float bb[HID];
    for (int i = threadIdx.x; i < 2 * F_IN * HID; i += 256) w[i] = W1[i];
    for (int i = threadIdx.x; i < F_IN * HID; i += 256) wr[i] = root1[i];
    if (threadIdx.x < HID) bb[threadIdx.x] = bias1[threadIdx.x];
    __syncthreads();
    int n = blockIdx.x * 256 + threadIdx.x;
    if (n >= NN) return;
    float accA[HID], accB[HID], accR[HID];
#pragma unroll
    for (int o = 0; o < HID; ++o) { accA[o] = 0.f; accB[o] = 0.f; accR[o] = bb[o]; }
    const float* xr = x + (size_t)n * F_IN;
    for (int f = 0; f < F_IN; ++f) {
        float xv = xr[f];
        const float* w0 = &w[f * HID];
        const float* w1 = &w[F_IN * HID + f * HID];
        const float* w2 = &wr[f * HID];
#pragma unroll
        for (int o = 0; o < HID; ++o) {
            accA[o] = fmaf(xv, w0[o], accA[o]);
            accB[o] = fmaf(xv, w1[o], accB[o]);
            accR[o] = fmaf(xv, w2[o], accR[o]);
        }
    }
    float2* ar = ab1 + (size_t)n * HID;
    float* rr = r1 + (size_t)n * HID;
#pragma unroll
    for (int o = 0; o < HID; ++o) {
        ar[o] = make_float2(accA[o], accB[o] - accA[o]);
        rr[o] = accR[o];
    }
}

// ---------------- layer-1 bucketed gather + mean + root + ELU -> h (+1/deg) ----------------
__global__ __launch_bounds__(256) void gather1_kernel(const int* __restrict__ bbase,
                                                      const int2* __restrict__ bkt,
                                                      const float2* __restrict__ ab1,
                                                      const float* __restrict__ r1,
                                                      float* __restrict__ h,
                                                      float* __restrict__ dinv) {
    __shared__ float acc[BKT_NODES * HID];  // 4 KB
    __shared__ float degs[BKT_NODES];
    int t = threadIdx.x;
    for (int i = t; i < BKT_NODES * HID; i += 256) acc[i] = 0.f;
    if (t < BKT_NODES) degs[t] = 0.f;
    __syncthreads();
    int b = blockIdx.x;
    int beg = bbase[b], end = bbase[b + 1];
    int j = t & (HID - 1);
    int g = t >> 4;  // 16 groups
    for (int e = beg + g; e < end; e += 16) {
        int2 pk = bkt[e];
        int loc = pk.x >> 17;
        float u = __int_as_float(pk.y);
        float2 ab = ab1[(size_t)(pk.x & 0x1FFFF) * HID + j];
        atomicAdd(&acc[loc * HID + j], fmaf(u, ab.y, ab.x));
        if (j == 0) atomicAdd(&degs[loc], 1.f);
    }
    __syncthreads();
    if (t < BKT_NODES) degs[t] = 1.f / fmaxf(degs[t], 1.f);
    __syncthreads();
    int nodeBase = b * BKT_NODES;
#pragma unroll
    for (int it = 0; it < BKT_NODES * HID / 256; ++it) {  // 4
        int idx = it * 256 + t;
        int nl = idx >> 4, jj = idx & (HID - 1);
        int n = nodeBase + nl;
        if (n < NN) {
            float v = acc[idx] * degs[nl] + r1[(size_t)n * HID + jj];
            h[(size_t)n * HID + jj] = v > 0.f ? v : expm1f(v);
        }
    }
    if (t < BKT_NODES && nodeBase + t < NN) dinv[nodeBase + t] = degs[t];
}

// ---------------- layer-2 projection ----------------
__global__ __launch_bounds__(256) void proj2_kernel(const float* __restrict__ h,
                                                    const float* __restrict__ W2,
                                                    float2* __restrict__ ab2) {
    __shared__ float w[2 * HID * OUTF];
    for (int i = threadIdx.x; i < 2 * HID * OUTF; i += 256) w[i] = W2[i];
    __syncthreads();
    int n = blockIdx.x * 256 + threadIdx.x;
    if (n >= NN) return;
    float accA[OUTF], accB[OUTF];
#pragma unroll
    for (int o = 0; o < OUTF; ++o) { accA[o] = 0.f; accB[o] = 0.f; }
    const float* hr = h + (size_t)n * HID;
#pragma unroll
    for (int f = 0; f < HID; ++f) {
        float hv = hr[f];
        const float* w0 = &w[f * OUTF];
        const float* w1 = &w[HID * OUTF + f * OUTF];
#pragma unroll
        for (int o = 0; o < OUTF; ++o) {
            accA[o] = fmaf(hv, w0[o], accA[o]);
            accB[o] = fmaf(hv, w1[o], accB[o]);
        }
    }
    float2* ar = ab2 + (size_t)n * OUTF;
#pragma unroll
    for (int o = 0; o < OUTF; ++o) ar[o] = make_float2(accA[o], accB[o] - accA[o]);
}

// ---------------- layer-2 bucketed gather + mean + root + log_softmax -> out ----------------
__global__ __launch_bounds__(256) void gather2_kernel(const int* __restrict__ bbase,
                                                      const int2* __restrict__ bkt,
                                                      const float2* __restrict__ ab2,
                                                      const float* __restrict__ h,
                                                      const float* __restrict__ root2,
                                                      const float* __restrict__ bias2,
                                                      const float* __restrict__ dinv,
                                                      float* __restrict__ out) {
    __shared__ float acc[BKT_NODES * OUTF];  // 8 KB
    __shared__ float w[HID * OUTF];          // 512
    __shared__ float bb[OUTF];
    int t = threadIdx.x;
    for (int i = t; i < HID * OUTF; i += 256) w[i] = root2[i];
    if (t < OUTF) bb[t] = bias2[t];
    for (int i = t; i < BKT_NODES * OUTF; i += 256) acc[i] = 0.f;
    __syncthreads();
    int b = blockIdx.x;
    int beg = bbase[b], end = bbase[b + 1];
    int j = t & (OUTF - 1);
    int g = t >> 5;  // 8 groups
    for (int e = beg + g; e < end; e += 8) {
        int2 pk = bkt[e];
        int loc = pk.x >> 17;
        float u = __int_as_float(pk.y);
        float2 ab = ab2[(size_t)(pk.x & 0x1FFFF) * OUTF + j];
        atomicAdd(&acc[loc * OUTF + j], fmaf(u, ab.y, ab.x));
    }
    __syncthreads();
    int nodeBase = b * BKT_NODES;
#pragma unroll
    for (int it = 0; it < BKT_NODES * OUTF / 256; ++it) {  // 8
        int idx = it * 256 + t;
        int nl = idx >> 5, jj = idx & (OUTF - 1);
        int n = nodeBase + nl;
        float v = 0.f;
        if (n < NN) {
            v = acc[idx] * dinv[n] + bb[jj];
            const float* hr = h + (size_t)n * HID;
#pragma unroll
            for (int f = 0; f < HID; ++f) v = fmaf(hr[f], w[f * OUTF + jj], v);
        }
        float m = v;
#pragma unroll
        for (int mask = 16; mask >= 1; mask >>= 1) m = fmaxf(m, __shfl_xor(m, mask));
        float ex = expf(v - m);
        float s = ex;
#pragma unroll
        for (int mask = 16; mask >= 1; mask >>= 1) s += __shfl_xor(s, mask);
        if (n < NN) out[(size_t)n * OUTF + jj] = v - m - logf(s);
    }
}

extern "C" void kernel_launch(void* const* d_in, const int* in_sizes, int n_in,
                              void* d_out, int out_size, void* d_ws, size_t ws_size,
                              hipStream_t stream) {
    const float* x     = (const float*)d_in[0];
    const int*   ei    = (const int*)d_in[1];
    const float* ea    = (const float*)d_in[3];
    const float* W1    = (const float*)d_in[4];
    const float* root1 = (const float*)d_in[5];
    const float* bias1 = (const float*)d_in[6];
    const float* W2    = (const float*)d_in[7];
    const float* root2 = (const float*)d_in[8];
    const float* bias2 = (const float*)d_in[9];
    float* out = (float*)d_out;
    float* ws  = (float*)d_ws;

    const size_t N = NN;
    // workspace layout (float units): header 310000 + h 16N + bkt 32N + AB 64N = 46.05 MB
    int*    hist  = (int*)(ws);                    // 100032
    int*    base  = (int*)(ws + 100032);           // 100032
    int*    bbase = (int*)(ws + 200064);           // 1564
    float*  dinv  = ws + 201664;                   // 100000
    float*  h     = ws + 310000;                   // 16N
    int2*   bkt   = (int2*)(ws + 310000 + 16 * N); // 32N floats
    float*  AB    = ws + 310000 + 48 * N;          // 64N floats
    float2* ab1   = (float2*)AB;                   // 32N floats
    float*  r1    = AB + 32 * N;                   // 16N floats
    float2* ab2   = (float2*)AB;                   // 64N floats (ab1/r1 dead by then)

    int nbN = (NN + 255) / 256;
    histA_kernel<<<PBLK, 256, 0, stream>>>(ei, hist);
    scanB_kernel<<<1, 1024, 0, stream>>>(hist, base, bbase);
    scatterC_kernel<<<PBLK, 256, 0, stream>>>(ei, ea, base, bkt);

    proj1_kernel<<<nbN, 256, 0, stream>>>(x, W1, root1, bias1, ab1, r1);
    gather1_kernel<<<NBKT, 256, 0, stream>>>(bbase, bkt, ab1, r1, h, dinv);
    proj2_kernel<<<nbN, 256, 0, stream>>>(h, W2, ab2);
    gather2_kernel<<<NBKT, 256, 0, stream>>>(bbase, bkt, ab2, h, root2, bias2, dinv, out);
}

// Round 5
// 718.323 us; speedup vs baseline: 1.9916x; 1.0771x over previous
//
#include <hip/hip_runtime.h>
#include <math.h>

#define NN 100000
#define NE 1600000
#define F_IN 64
#define HID 16
#define OUTF 32
#define BKT_SHIFT 6
#define BKT_NODES 64
#define NBKT 1563               // ceil(NN/64)
#define PBLK 64                 // partition blocks (keeps 16-edge runs per (bkt,blk))
#define EPB (NE / PBLK)         // 25000
#define M_HIST (NBKT * PBLK)    // 100032
#define SRCM 0x1FFFF

// ---------------- A: per-block bucket histogram (LDS atomics only) ----------------
__global__ __launch_bounds__(1024) void histA_kernel(const int* __restrict__ ei,
                                                     int* __restrict__ hist) {
    __shared__ int hcnt[NBKT];
    int t = threadIdx.x, blk = blockIdx.x;
    for (int i = t; i < NBKT; i += 1024) hcnt[i] = 0;
    __syncthreads();
    int beg = blk * EPB, end = beg + EPB;
    for (int e = beg + t; e < end; e += 1024)
        atomicAdd(&hcnt[ei[NE + e] >> BKT_SHIFT], 1);
    __syncthreads();
    for (int i = t; i < NBKT; i += 1024) hist[i * PBLK + blk] = hcnt[i];
}

// ---------------- B: exclusive scan over [bkt][blk] matrix (one block) ----------------
__global__ __launch_bounds__(1024) void scanB_kernel(const int* __restrict__ hist,
                                                     int* __restrict__ base,
                                                     int* __restrict__ bbase) {
    __shared__ int s[1024];
    int t = threadIdx.x;
    const int PER = (M_HIST + 1023) / 1024;  // 98
    int lo = t * PER;
    int hi = lo + PER; if (hi > M_HIST) hi = M_HIST;
    int sum = 0;
    for (int i = lo; i < hi; ++i) sum += hist[i];
    s[t] = sum;
    __syncthreads();
    for (int off = 1; off < 1024; off <<= 1) {
        int xv = (t >= off) ? s[t - off] : 0;
        __syncthreads();
        s[t] += xv;
        __syncthreads();
    }
    int run = (t == 0) ? 0 : s[t - 1];
    for (int i = lo; i < hi; ++i) {
        base[i] = run;
        if ((i & (PBLK - 1)) == 0) bbase[i / PBLK] = run;
        run += hist[i];
    }
    if (t == 1023) bbase[NBKT] = NE;
}

// ---------------- C: partition edges (LDS cursors, no global atomics) ----------------
__global__ __launch_bounds__(1024) void scatterC_kernel(const int* __restrict__ ei,
                                                        const float* __restrict__ ea,
                                                        const int* __restrict__ base,
                                                        int2* __restrict__ bkt) {
    __shared__ int cur[NBKT];
    int t = threadIdx.x, blk = blockIdx.x;
    for (int i = t; i < NBKT; i += 1024) cur[i] = base[i * PBLK + blk];
    __syncthreads();
    int beg = blk * EPB, end = beg + EPB;
    for (int e = beg + t; e < end; e += 1024) {
        int src = ei[e];
        int dst = ei[NE + e];
        float u = ea[e];
        int b = dst >> BKT_SHIFT;
        int p = atomicAdd(&cur[b], 1);
        bkt[p] = make_int2(src | ((dst & (BKT_NODES - 1)) << 17), __float_as_int(u));
    }
}

// ---------------- layer-1 projection: ab1 = (a, b-a); r1 = x@root1 + bias1 ----------------
__global__ __launch_bounds__(256) void proj1_kernel(const float* __restrict__ x,
                                                    const float* __restrict__ W1,
                                                    const float* __restrict__ root1,
                                                    const float* __restrict__ bias1,
                                                    float2* __restrict__ ab1,
                                                    float* __restrict__ r1) {
    __shared__ float w[2 * F_IN * HID];
    __shared__ float wr[F_IN * HID];
    __shared__ float bb[HID];
    for (int i = threadIdx.x; i < 2 * F_IN * HID; i += 256) w[i] = W1[i];
    for (int i = threadIdx.x; i < F_IN * HID; i += 256) wr[i] = root1[i];
    if (threadIdx.x < HID) bb[threadIdx.x] = bias1[threadIdx.x];
    __syncthreads();
    int n = blockIdx.x * 256 + threadIdx.x;
    if (n >= NN) return;
    float accA[HID], accB[HID], accR[HID];
#pragma unroll
    for (int o = 0; o < HID; ++o) { accA[o] = 0.f; accB[o] = 0.f; accR[o] = bb[o]; }
    const float* xr = x + (size_t)n * F_IN;
    for (int f = 0; f < F_IN; ++f) {
        float xv = xr[f];
        const float* w0 = &w[f * HID];
        const float* w1 = &w[F_IN * HID + f * HID];
        const float* w2 = &wr[f * HID];
#pragma unroll
        for (int o = 0; o < HID; ++o) {
            accA[o] = fmaf(xv, w0[o], accA[o]);
            accB[o] = fmaf(xv, w1[o], accB[o]);
            accR[o] = fmaf(xv, w2[o], accR[o]);
        }
    }
    float2* ar = ab1 + (size_t)n * HID;
    float* rr = r1 + (size_t)n * HID;
#pragma unroll
    for (int o = 0; o < HID; ++o) {
        ar[o] = make_float2(accA[o], accB[o] - accA[o]);
        rr[o] = accR[o];
    }
}

// ---------------- layer-1 bucketed gather (4x unrolled) + mean + root + ELU -> h ----------------
__global__ __launch_bounds__(512) void gather1_kernel(const int* __restrict__ bbase,
                                                      const int2* __restrict__ bkt,
                                                      const float2* __restrict__ ab1,
                                                      const float* __restrict__ r1,
                                                      float* __restrict__ h,
                                                      float* __restrict__ dinv) {
    __shared__ float acc[BKT_NODES * HID];  // 4 KB
    __shared__ float degs[BKT_NODES];
    int t = threadIdx.x;
    for (int i = t; i < BKT_NODES * HID; i += 512) acc[i] = 0.f;
    if (t < BKT_NODES) degs[t] = 0.f;
    __syncthreads();
    int b = blockIdx.x;
    int beg = bbase[b], end = bbase[b + 1];
    int j = t & (HID - 1);
    int g = t >> 4;  // 32 groups of 16
    int e = beg + g;
    for (; e + 96 < end; e += 128) {
        int2 p0 = bkt[e];
        int2 p1 = bkt[e + 32];
        int2 p2 = bkt[e + 64];
        int2 p3 = bkt[e + 96];
        float2 v0 = ab1[(size_t)(p0.x & SRCM) * HID + j];
        float2 v1 = ab1[(size_t)(p1.x & SRCM) * HID + j];
        float2 v2 = ab1[(size_t)(p2.x & SRCM) * HID + j];
        float2 v3 = ab1[(size_t)(p3.x & SRCM) * HID + j];
        atomicAdd(&acc[(p0.x >> 17) * HID + j], fmaf(__int_as_float(p0.y), v0.y, v0.x));
        atomicAdd(&acc[(p1.x >> 17) * HID + j], fmaf(__int_as_float(p1.y), v1.y, v1.x));
        atomicAdd(&acc[(p2.x >> 17) * HID + j], fmaf(__int_as_float(p2.y), v2.y, v2.x));
        atomicAdd(&acc[(p3.x >> 17) * HID + j], fmaf(__int_as_float(p3.y), v3.y, v3.x));
        if (j == 0) {
            atomicAdd(&degs[p0.x >> 17], 1.f);
            atomicAdd(&degs[p1.x >> 17], 1.f);
            atomicAdd(&degs[p2.x >> 17], 1.f);
            atomicAdd(&degs[p3.x >> 17], 1.f);
        }
    }
    for (; e < end; e += 32) {
        int2 pk = bkt[e];
        float2 ab = ab1[(size_t)(pk.x & SRCM) * HID + j];
        atomicAdd(&acc[(pk.x >> 17) * HID + j], fmaf(__int_as_float(pk.y), ab.y, ab.x));
        if (j == 0) atomicAdd(&degs[pk.x >> 17], 1.f);
    }
    __syncthreads();
    if (t < BKT_NODES) degs[t] = 1.f / fmaxf(degs[t], 1.f);
    __syncthreads();
    int nodeBase = b * BKT_NODES;
#pragma unroll
    for (int it = 0; it < BKT_NODES * HID / 512; ++it) {  // 2
        int idx = it * 512 + t;
        int nl = idx >> 4, jj = idx & (HID - 1);
        int n = nodeBase + nl;
        if (n < NN) {
            float v = acc[idx] * degs[nl] + r1[(size_t)n * HID + jj];
            h[(size_t)n * HID + jj] = v > 0.f ? v : expm1f(v);
        }
    }
    if (t < BKT_NODES && nodeBase + t < NN) dinv[nodeBase + t] = degs[t];
}

// ---- layer-2: aggregate S0=Σh[src], S1=Σu*h[src]; then (S0@W20 + S1@W2d)/deg + h@root2 + bias, log_softmax ----
__global__ __launch_bounds__(512) void gather2_kernel(const int* __restrict__ bbase,
                                                      const int2* __restrict__ bkt,
                                                      const float* __restrict__ h,
                                                      const float* __restrict__ W2,
                                                      const float* __restrict__ root2,
                                                      const float* __restrict__ bias2,
                                                      const float* __restrict__ dinv,
                                                      float* __restrict__ out) {
    __shared__ float s0[BKT_NODES * HID];   // 4 KB
    __shared__ float s1[BKT_NODES * HID];   // 4 KB
    __shared__ float w20[HID * OUTF];       // W2[0]
    __shared__ float w2d[HID * OUTF];       // W2[1]-W2[0]
    __shared__ float wr[HID * OUTF];        // root2
    __shared__ float bb[OUTF];
    int t = threadIdx.x;
    for (int i = t; i < HID * OUTF; i += 512) {
        float a = W2[i];
        w20[i] = a;
        w2d[i] = W2[HID * OUTF + i] - a;
        wr[i] = root2[i];
    }
    if (t < OUTF) bb[t] = bias2[t];
    for (int i = t; i < BKT_NODES * HID; i += 512) { s0[i] = 0.f; s1[i] = 0.f; }
    __syncthreads();
    int b = blockIdx.x;
    int beg = bbase[b], end = bbase[b + 1];
    int j = t & (HID - 1);
    int g = t >> 4;  // 32 groups of 16
    int e = beg + g;
    for (; e + 96 < end; e += 128) {
        int2 p0 = bkt[e];
        int2 p1 = bkt[e + 32];
        int2 p2 = bkt[e + 64];
        int2 p3 = bkt[e + 96];
        float h0 = h[(size_t)(p0.x & SRCM) * HID + j];
        float h1 = h[(size_t)(p1.x & SRCM) * HID + j];
        float h2 = h[(size_t)(p2.x & SRCM) * HID + j];
        float h3 = h[(size_t)(p3.x & SRCM) * HID + j];
        int l0 = p0.x >> 17, l1 = p1.x >> 17, l2 = p2.x >> 17, l3 = p3.x >> 17;
        atomicAdd(&s0[l0 * HID + j], h0);
        atomicAdd(&s1[l0 * HID + j], __int_as_float(p0.y) * h0);
        atomicAdd(&s0[l1 * HID + j], h1);
        atomicAdd(&s1[l1 * HID + j], __int_as_float(p1.y) * h1);
        atomicAdd(&s0[l2 * HID + j], h2);
        atomicAdd(&s1[l2 * HID + j], __int_as_float(p2.y) * h2);
        atomicAdd(&s0[l3 * HID + j], h3);
        atomicAdd(&s1[l3 * HID + j], __int_as_float(p3.y) * h3);
    }
    for (; e < end; e += 32) {
        int2 pk = bkt[e];
        float hv = h[(size_t)(pk.x & SRCM) * HID + j];
        int l = pk.x >> 17;
        atomicAdd(&s0[l * HID + j], hv);
        atomicAdd(&s1[l * HID + j], __int_as_float(pk.y) * hv);
    }
    __syncthreads();
    int nodeBase = b * BKT_NODES;
#pragma unroll
    for (int it = 0; it < BKT_NODES * OUTF / 512; ++it) {  // 4
        int idx = it * 512 + t;
        int nl = idx >> 5, jj = idx & (OUTF - 1);
        int n = nodeBase + nl;
        float v = 0.f;
        if (n < NN) {
            float msum = 0.f;
            const float* S0 = &s0[nl * HID];
            const float* S1 = &s1[nl * HID];
#pragma unroll
            for (int f = 0; f < HID; ++f)
                msum += S0[f] * w20[f * OUTF + jj] + S1[f] * w2d[f * OUTF + jj];
            v = msum * dinv[n] + bb[jj];
            const float* hr = h + (size_t)n * HID;
#pragma unroll
            for (int f = 0; f < HID; ++f) v = fmaf(hr[f], wr[f * OUTF + jj], v);
        }
        float m = v;
#pragma unroll
        for (int mask = 16; mask >= 1; mask >>= 1) m = fmaxf(m, __shfl_xor(m, mask));
        float ex = expf(v - m);
        float s = ex;
#pragma unroll
        for (int mask = 16; mask >= 1; mask >>= 1) s += __shfl_xor(s, mask);
        if (n < NN) out[(size_t)n * OUTF + jj] = v - m - logf(s);
    }
}

extern "C" void kernel_launch(void* const* d_in, const int* in_sizes, int n_in,
                              void* d_out, int out_size, void* d_ws, size_t ws_size,
                              hipStream_t stream) {
    const float* x     = (const float*)d_in[0];
    const int*   ei    = (const int*)d_in[1];
    const float* ea    = (const float*)d_in[3];
    const float* W1    = (const float*)d_in[4];
    const float* root1 = (const float*)d_in[5];
    const float* bias1 = (const float*)d_in[6];
    const float* W2    = (const float*)d_in[7];
    const float* root2 = (const float*)d_in[8];
    const float* bias2 = (const float*)d_in[9];
    float* out = (float*)d_out;
    float* ws  = (float*)d_ws;

    const size_t N = NN;
    // workspace (float units): header ~302K + h 16N + bkt 32N + ab1 32N + r1 16N ≈ 39.7 MB
    int*    hist  = (int*)(ws);                    // 100032
    int*    base  = (int*)(ws + 100032);           // 100032
    int*    bbase = (int*)(ws + 200064);           // 1564
    float*  dinv  = ws + 201664;                   // 100000
    float*  h     = ws + 302000;                   // 16N
    int2*   bkt   = (int2*)(ws + 302000 + 16 * N); // 32N floats
    float2* ab1   = (float2*)(ws + 302000 + 48 * N); // 32N floats
    float*  r1    = ws + 302000 + 80 * N;          // 16N floats

    int nbN = (NN + 255) / 256;
    histA_kernel<<<PBLK, 1024, 0, stream>>>(ei, hist);
    scanB_kernel<<<1, 1024, 0, stream>>>(hist, base, bbase);
    scatterC_kernel<<<PBLK, 1024, 0, stream>>>(ei, ea, base, bkt);

    proj1_kernel<<<nbN, 256, 0, stream>>>(x, W1, root1, bias1, ab1, r1);
    gather1_kernel<<<NBKT, 512, 0, stream>>>(bbase, bkt, ab1, r1, h, dinv);
    gather2_kernel<<<NBKT, 512, 0, stream>>>(bbase, bkt, h, W2, root2, bias2, dinv, out);
}

// Round 6
// 338.705 us; speedup vs baseline: 4.2239x; 2.1208x over previous
//
#include <hip/hip_runtime.h>
#include <math.h>

#define NN 100000
#define NE 1600000
#define F_IN 64
#define HID 16
#define OUTF 32
#define BKT_SHIFT 6
#define BKT_NODES 64
#define NBKT 1563               // ceil(NN/64)
#define PBLK 64                 // partition blocks
#define EPB (NE / PBLK)         // 25000
#define M_HIST (NBKT * PBLK)    // 100032
#define SRCM 0x1FFFF
#define CAP 1536                // per-bucket LDS edge capacity (mean 1024, sd 32)

// ---------------- A: per-block bucket histogram (LDS atomics only) ----------------
__global__ __launch_bounds__(1024) void histA_kernel(const int* __restrict__ ei,
                                                     int* __restrict__ hist) {
    __shared__ int hcnt[NBKT];
    int t = threadIdx.x, blk = blockIdx.x;
    for (int i = t; i < NBKT; i += 1024) hcnt[i] = 0;
    __syncthreads();
    int beg = blk * EPB, end = beg + EPB;
    for (int e = beg + t; e < end; e += 1024)
        atomicAdd(&hcnt[ei[NE + e] >> BKT_SHIFT], 1);
    __syncthreads();
    for (int i = t; i < NBKT; i += 1024) hist[i * PBLK + blk] = hcnt[i];
}

// ---------------- B: exclusive scan over [bkt][blk] matrix (one block) ----------------
__global__ __launch_bounds__(1024) void scanB_kernel(const int* __restrict__ hist,
                                                     int* __restrict__ base,
                                                     int* __restrict__ bbase) {
    __shared__ int s[1024];
    int t = threadIdx.x;
    const int PER = (M_HIST + 1023) / 1024;  // 98
    int lo = t * PER;
    int hi = lo + PER; if (hi > M_HIST) hi = M_HIST;
    int sum = 0;
    for (int i = lo; i < hi; ++i) sum += hist[i];
    s[t] = sum;
    __syncthreads();
    for (int off = 1; off < 1024; off <<= 1) {
        int xv = (t >= off) ? s[t - off] : 0;
        __syncthreads();
        s[t] += xv;
        __syncthreads();
    }
    int run = (t == 0) ? 0 : s[t - 1];
    for (int i = lo; i < hi; ++i) {
        base[i] = run;
        if ((i & (PBLK - 1)) == 0) bbase[i / PBLK] = run;
        run += hist[i];
    }
    if (t == 1023) bbase[NBKT] = NE;
}

// ---------------- C: partition edges (LDS cursors, no global atomics) ----------------
__global__ __launch_bounds__(1024) void scatterC_kernel(const int* __restrict__ ei,
                                                        const float* __restrict__ ea,
                                                        const int* __restrict__ base,
                                                        int2* __restrict__ bkt) {
    __shared__ int cur[NBKT];
    int t = threadIdx.x, blk = blockIdx.x;
    for (int i = t; i < NBKT; i += 1024) cur[i] = base[i * PBLK + blk];
    __syncthreads();
    int beg = blk * EPB, end = beg + EPB;
    for (int e = beg + t; e < end; e += 1024) {
        int src = ei[e];
        int dst = ei[NE + e];
        float u = ea[e];
        int b = dst >> BKT_SHIFT;
        int p = atomicAdd(&cur[b], 1);
        bkt[p] = make_int2(src | ((dst & (BKT_NODES - 1)) << 17), __float_as_int(u));
    }
}

// ---------------- layer-1 projection: ab1 = (a, b-a); r1 = x@root1 + bias1 ----------------
__global__ __launch_bounds__(256) void proj1_kernel(const float* __restrict__ x,
                                                    const float* __restrict__ W1,
                                                    const float* __restrict__ root1,
                                                    const float* __restrict__ bias1,
                                                    float2* __restrict__ ab1,
                                                    float* __restrict__ r1) {
    __shared__ float w[2 * F_IN * HID];
    __shared__ float wr[F_IN * HID];
    __shared__ float bb[HID];
    for (int i = threadIdx.x; i < 2 * F_IN * HID; i += 256) w[i] = W1[i];
    for (int i = threadIdx.x; i < F_IN * HID; i += 256) wr[i] = root1[i];
    if (threadIdx.x < HID) bb[threadIdx.x] = bias1[threadIdx.x];
    __syncthreads();
    int n = blockIdx.x * 256 + threadIdx.x;
    if (n >= NN) return;
    float accA[HID], accB[HID], accR[HID];
#pragma unroll
    for (int o = 0; o < HID; ++o) { accA[o] = 0.f; accB[o] = 0.f; accR[o] = bb[o]; }
    const float* xr = x + (size_t)n * F_IN;
    for (int f = 0; f < F_IN; ++f) {
        float xv = xr[f];
        const float* w0 = &w[f * HID];
        const float* w1 = &w[F_IN * HID + f * HID];
        const float* w2 = &wr[f * HID];
#pragma unroll
        for (int o = 0; o < HID; ++o) {
            accA[o] = fmaf(xv, w0[o], accA[o]);
            accB[o] = fmaf(xv, w1[o], accB[o]);
            accR[o] = fmaf(xv, w2[o], accR[o]);
        }
    }
    float2* ar = ab1 + (size_t)n * HID;
    float* rr = r1 + (size_t)n * HID;
#pragma unroll
    for (int o = 0; o < HID; ++o) {
        ar[o] = make_float2(accA[o], accB[o] - accA[o]);
        rr[o] = accR[o];
    }
}

// ---- layer-1: sort bucket edges by local node in LDS, register-accumulate, ELU -> h ----
__global__ __launch_bounds__(512) void gather1_kernel(const int* __restrict__ bbase,
                                                      const int2* __restrict__ bkt,
                                                      const float2* __restrict__ ab1,
                                                      const float* __restrict__ r1,
                                                      float* __restrict__ h,
                                                      float* __restrict__ dinv) {
    __shared__ int2 sorted[CAP];            // 12 KB
    __shared__ int cnt[BKT_NODES], cur[BKT_NODES], segb[BKT_NODES + 1];
    __shared__ float accL[BKT_NODES * HID]; // legacy path only
    __shared__ float degsL[BKT_NODES];
    int t = threadIdx.x;
    int b = blockIdx.x;
    int beg = bbase[b], end = bbase[b + 1];
    int tot = end - beg;
    if (t < BKT_NODES) { cnt[t] = 0; cur[t] = 0; degsL[t] = 0.f; }
    __syncthreads();
    int nodeBase = b * BKT_NODES;

    if (tot <= CAP) {
        // ---- fast path ----
        for (int e = beg + t; e < end; e += 512)
            atomicAdd(&cnt[((unsigned)bkt[e].x) >> 17], 1);
        __syncthreads();
        if (t < BKT_NODES) {
            int v = cnt[t];
            int sc = v;
#pragma unroll
            for (int off = 1; off < 64; off <<= 1) {
                int o = __shfl_up(sc, off, 64);
                if (t >= off) sc += o;
            }
            segb[t] = sc - v;
            if (t == 63) segb[64] = sc;
        }
        __syncthreads();
        for (int e = beg + t; e < end; e += 512) {
            int2 pk = bkt[e];
            int loc = ((unsigned)pk.x) >> 17;
            int pos = segb[loc] + atomicAdd(&cur[loc], 1);
            sorted[pos] = pk;
        }
        __syncthreads();
        int j = t & (HID - 1);
        int g = t >> 4;                 // 32 groups, nodes 2g, 2g+1
        int s = segb[2 * g], mid = segb[2 * g + 1], e2 = segb[2 * g + 2];
        float a0 = 0.f, a1 = 0.f;
        int e = s;
        for (; e + 8 <= e2; e += 8) {
            float val[8]; int sel[8];
#pragma unroll
            for (int k = 0; k < 8; ++k) {
                int2 pk = sorted[e + k];
                float2 ab = ab1[(size_t)(pk.x & SRCM) * HID + j];
                val[k] = fmaf(__int_as_float(pk.y), ab.y, ab.x);
                sel[k] = (e + k) >= mid;
            }
#pragma unroll
            for (int k = 0; k < 8; ++k) {
                a0 += sel[k] ? 0.f : val[k];
                a1 += sel[k] ? val[k] : 0.f;
            }
        }
        for (; e < e2; ++e) {
            int2 pk = sorted[e];
            float2 ab = ab1[(size_t)(pk.x & SRCM) * HID + j];
            float val = fmaf(__int_as_float(pk.y), ab.y, ab.x);
            if (e >= mid) a1 += val; else a0 += val;
        }
        float d0 = 1.f / (float)max(mid - s, 1);
        float d1 = 1.f / (float)max(e2 - mid, 1);
        int n0 = nodeBase + 2 * g, n1 = n0 + 1;
        if (n0 < NN) {
            float v = a0 * d0 + r1[(size_t)n0 * HID + j];
            h[(size_t)n0 * HID + j] = v > 0.f ? v : expm1f(v);
            if (j == 0) dinv[n0] = d0;
        }
        if (n1 < NN) {
            float v = a1 * d1 + r1[(size_t)n1 * HID + j];
            h[(size_t)n1 * HID + j] = v > 0.f ? v : expm1f(v);
            if (j == 0) dinv[n1] = d1;
        }
    } else {
        // ---- legacy atomic path (bucket overflow; statistically never) ----
        for (int i = t; i < BKT_NODES * HID; i += 512) accL[i] = 0.f;
        __syncthreads();
        int j = t & (HID - 1);
        int g = t >> 4;
        for (int e = beg + g; e < end; e += 32) {
            int2 pk = bkt[e];
            float2 ab = ab1[(size_t)(pk.x & SRCM) * HID + j];
            atomicAdd(&accL[(pk.x >> 17) * HID + j], fmaf(__int_as_float(pk.y), ab.y, ab.x));
            if (j == 0) atomicAdd(&degsL[pk.x >> 17], 1.f);
        }
        __syncthreads();
        if (t < BKT_NODES) degsL[t] = 1.f / fmaxf(degsL[t], 1.f);
        __syncthreads();
#pragma unroll
        for (int it = 0; it < BKT_NODES * HID / 512; ++it) {
            int idx = it * 512 + t;
            int nl = idx >> 4, jj = idx & (HID - 1);
            int n = nodeBase + nl;
            if (n < NN) {
                float v = accL[idx] * degsL[nl] + r1[(size_t)n * HID + jj];
                h[(size_t)n * HID + jj] = v > 0.f ? v : expm1f(v);
            }
        }
        if (t < BKT_NODES && nodeBase + t < NN) dinv[nodeBase + t] = degsL[t];
    }
}

// ---- layer-2: sorted register-accumulate S0=Σh, S1=Σu·h; project + root + log_softmax ----
__global__ __launch_bounds__(512) void gather2_kernel(const int* __restrict__ bbase,
                                                      const int2* __restrict__ bkt,
                                                      const float* __restrict__ h,
                                                      const float* __restrict__ W2,
                                                      const float* __restrict__ root2,
                                                      const float* __restrict__ bias2,
                                                      const float* __restrict__ dinv,
                                                      float* __restrict__ out) {
    __shared__ int2 sorted[CAP];            // 12 KB
    __shared__ int cnt[BKT_NODES], cur[BKT_NODES], segb[BKT_NODES + 1];
    __shared__ float s0L[BKT_NODES * HID];  // 4 KB
    __shared__ float s1L[BKT_NODES * HID];  // 4 KB
    __shared__ float w20[HID * OUTF], w2d[HID * OUTF], wr[HID * OUTF];
    __shared__ float bb[OUTF];
    int t = threadIdx.x;
    for (int i = t; i < HID * OUTF; i += 512) {
        float a = W2[i];
        w20[i] = a;
        w2d[i] = W2[HID * OUTF + i] - a;
        wr[i] = root2[i];
    }
    if (t < OUTF) bb[t] = bias2[t];
    if (t < BKT_NODES) { cnt[t] = 0; cur[t] = 0; }
    int b = blockIdx.x;
    int beg = bbase[b], end = bbase[b + 1];
    int tot = end - beg;
    __syncthreads();

    if (tot <= CAP) {
        for (int e = beg + t; e < end; e += 512)
            atomicAdd(&cnt[((unsigned)bkt[e].x) >> 17], 1);
        __syncthreads();
        if (t < BKT_NODES) {
            int v = cnt[t];
            int sc = v;
#pragma unroll
            for (int off = 1; off < 64; off <<= 1) {
                int o = __shfl_up(sc, off, 64);
                if (t >= off) sc += o;
            }
            segb[t] = sc - v;
            if (t == 63) segb[64] = sc;
        }
        __syncthreads();
        for (int e = beg + t; e < end; e += 512) {
            int2 pk = bkt[e];
            int loc = ((unsigned)pk.x) >> 17;
            int pos = segb[loc] + atomicAdd(&cur[loc], 1);
            sorted[pos] = pk;
        }
        __syncthreads();
        int j = t & (HID - 1);
        int g = t >> 4;
        int s = segb[2 * g], mid = segb[2 * g + 1], e2 = segb[2 * g + 2];
        float s00 = 0.f, s10 = 0.f, s01 = 0.f, s11 = 0.f;
        int e = s;
        for (; e + 8 <= e2; e += 8) {
            float hv[8], uv[8]; int sel[8];
#pragma unroll
            for (int k = 0; k < 8; ++k) {
                int2 pk = sorted[e + k];
                hv[k] = h[(size_t)(pk.x & SRCM) * HID + j];
                uv[k] = __int_as_float(pk.y);
                sel[k] = (e + k) >= mid;
            }
#pragma unroll
            for (int k = 0; k < 8; ++k) {
                float uh = uv[k] * hv[k];
                s00 += sel[k] ? 0.f : hv[k];
                s10 += sel[k] ? 0.f : uh;
                s01 += sel[k] ? hv[k] : 0.f;
                s11 += sel[k] ? uh : 0.f;
            }
        }
        for (; e < e2; ++e) {
            int2 pk = sorted[e];
            float hvv = h[(size_t)(pk.x & SRCM) * HID + j];
            float uh = __int_as_float(pk.y) * hvv;
            if (e >= mid) { s01 += hvv; s11 += uh; }
            else          { s00 += hvv; s10 += uh; }
        }
        s0L[(2 * g) * HID + j] = s00;
        s1L[(2 * g) * HID + j] = s10;
        s0L[(2 * g + 1) * HID + j] = s01;
        s1L[(2 * g + 1) * HID + j] = s11;
        __syncthreads();
    } else {
        for (int i = t; i < BKT_NODES * HID; i += 512) { s0L[i] = 0.f; s1L[i] = 0.f; }
        __syncthreads();
        int j = t & (HID - 1);
        int g = t >> 4;
        for (int e = beg + g; e < end; e += 32) {
            int2 pk = bkt[e];
            float hvv = h[(size_t)(pk.x & SRCM) * HID + j];
            int l = pk.x >> 17;
            atomicAdd(&s0L[l * HID + j], hvv);
            atomicAdd(&s1L[l * HID + j], __int_as_float(pk.y) * hvv);
        }
        __syncthreads();
    }

    int nodeBase = b * BKT_NODES;
#pragma unroll
    for (int it = 0; it < BKT_NODES * OUTF / 512; ++it) {  // 4
        int idx = it * 512 + t;
        int nl = idx >> 5, jj = idx & (OUTF - 1);
        int n = nodeBase + nl;
        float v = 0.f;
        if (n < NN) {
            float msum = 0.f;
            const float* S0 = &s0L[nl * HID];
            const float* S1 = &s1L[nl * HID];
#pragma unroll
            for (int f = 0; f < HID; ++f)
                msum += S0[f] * w20[f * OUTF + jj] + S1[f] * w2d[f * OUTF + jj];
            v = msum * dinv[n] + bb[jj];
            const float* hr = h + (size_t)n * HID;
#pragma unroll
            for (int f = 0; f < HID; ++f) v = fmaf(hr[f], wr[f * OUTF + jj], v);
        }
        float m = v;
#pragma unroll
        for (int mask = 16; mask >= 1; mask >>= 1) m = fmaxf(m, __shfl_xor(m, mask));
        float ex = expf(v - m);
        float sm = ex;
#pragma unroll
        for (int mask = 16; mask >= 1; mask >>= 1) sm += __shfl_xor(sm, mask);
        if (n < NN) out[(size_t)n * OUTF + jj] = v - m - logf(sm);
    }
}

extern "C" void kernel_launch(void* const* d_in, const int* in_sizes, int n_in,
                              void* d_out, int out_size, void* d_ws, size_t ws_size,
                              hipStream_t stream) {
    const float* x     = (const float*)d_in[0];
    const int*   ei    = (const int*)d_in[1];
    const float* ea    = (const float*)d_in[3];
    const float* W1    = (const float*)d_in[4];
    const float* root1 = (const float*)d_in[5];
    const float* bias1 = (const float*)d_in[6];
    const float* W2    = (const float*)d_in[7];
    const float* root2 = (const float*)d_in[8];
    const float* bias2 = (const float*)d_in[9];
    float* out = (float*)d_out;
    float* ws  = (float*)d_ws;

    const size_t N = NN;
    int*    hist  = (int*)(ws);                      // 100032
    int*    base  = (int*)(ws + 100032);             // 100032
    int*    bbase = (int*)(ws + 200064);             // 1564
    float*  dinv  = ws + 201664;                     // 100000
    float*  h     = ws + 302000;                     // 16N
    int2*   bkt   = (int2*)(ws + 302000 + 16 * N);   // 32N floats
    float2* ab1   = (float2*)(ws + 302000 + 48 * N); // 32N floats
    float*  r1    = ws + 302000 + 80 * N;            // 16N floats

    int nbN = (NN + 255) / 256;
    histA_kernel<<<PBLK, 1024, 0, stream>>>(ei, hist);
    scanB_kernel<<<1, 1024, 0, stream>>>(hist, base, bbase);
    scatterC_kernel<<<PBLK, 1024, 0, stream>>>(ei, ea, base, bkt);

    proj1_kernel<<<nbN, 256, 0, stream>>>(x, W1, root1, bias1, ab1, r1);
    gather1_kernel<<<NBKT, 512, 0, stream>>>(bbase, bkt, ab1, r1, h, dinv);
    gather2_kernel<<<NBKT, 512, 0, stream>>>(bbase, bkt, h, W2, root2, bias2, dinv, out);
}

// Round 7
// 178.739 us; speedup vs baseline: 8.0041x; 1.8950x over previous
//
#include <hip/hip_runtime.h>
#include <math.h>

#define NN 100000
#define NE 1600000
#define F_IN 64
#define HID 16
#define OUTF 32
#define BKT_SHIFT 6
#define BKT_NODES 64
#define NBKT 1563               // ceil(NN/64)
#define PBLK 64                 // partition blocks
#define EPB (NE / PBLK)         // 25000
#define M_HIST (NBKT * PBLK)    // 100032
#define SRCM 0x1FFFF
#define CAP 1536                // per-bucket LDS edge capacity (mean 1024, sd 32)

// ---------------- A: per-block bucket histogram (LDS atomics only) ----------------
__global__ __launch_bounds__(1024) void histA_kernel(const int* __restrict__ ei,
                                                     int* __restrict__ hist) {
    __shared__ int hcnt[NBKT];
    int t = threadIdx.x, blk = blockIdx.x;
    for (int i = t; i < NBKT; i += 1024) hcnt[i] = 0;
    __syncthreads();
    int beg = blk * EPB, end = beg + EPB;
    for (int e = beg + t; e < end; e += 1024)
        atomicAdd(&hcnt[ei[NE + e] >> BKT_SHIFT], 1);
    __syncthreads();
    for (int i = t; i < NBKT; i += 1024) hist[i * PBLK + blk] = hcnt[i];
}

// ---------------- S1: per-bucket wave-scan of 64 per-block counts ----------------
__global__ __launch_bounds__(256) void scanS1_kernel(const int* __restrict__ hist,
                                                     int* __restrict__ base,
                                                     int* __restrict__ bktsum) {
    int lane = threadIdx.x & 63;
    int bkt = blockIdx.x * 4 + (threadIdx.x >> 6);
    if (bkt >= NBKT) return;
    int v = hist[bkt * PBLK + lane];
    int sc = v;
#pragma unroll
    for (int off = 1; off < 64; off <<= 1) {
        int o = __shfl_up(sc, off, 64);
        if (lane >= off) sc += o;
    }
    base[bkt * PBLK + lane] = sc - v;   // within-bucket exclusive
    if (lane == 63) bktsum[bkt] = sc;
}

// ---------------- S2: single-block scan of 1563 bucket totals -> bbase ----------------
__global__ __launch_bounds__(1024) void scanS2_kernel(const int* __restrict__ bktsum,
                                                      int* __restrict__ bbase) {
    __shared__ int s[1024];
    int t = threadIdx.x;
    int i0 = 2 * t, i1 = 2 * t + 1;
    int v0 = (i0 < NBKT) ? bktsum[i0] : 0;
    int v1 = (i1 < NBKT) ? bktsum[i1] : 0;
    s[t] = v0 + v1;
    __syncthreads();
    for (int off = 1; off < 1024; off <<= 1) {
        int xv = (t >= off) ? s[t - off] : 0;
        __syncthreads();
        s[t] += xv;
        __syncthreads();
    }
    int run = (t == 0) ? 0 : s[t - 1];
    if (i0 < NBKT) bbase[i0] = run;
    if (i1 < NBKT) bbase[i1] = run + v0;
    if (t == 1023) bbase[NBKT] = NE;
}

// ---------------- S3: add bucket offsets into per-(bkt,blk) bases ----------------
__global__ __launch_bounds__(256) void scanS3_kernel(int* __restrict__ base,
                                                     const int* __restrict__ bbase) {
    int i = blockIdx.x * 256 + threadIdx.x;
    if (i < M_HIST) base[i] += bbase[i >> 6];   // i/PBLK = bkt (PBLK==64)
}

// ---------------- C: partition edges (LDS cursors, no global atomics) ----------------
__global__ __launch_bounds__(1024) void scatterC_kernel(const int* __restrict__ ei,
                                                        const float* __restrict__ ea,
                                                        const int* __restrict__ base,
                                                        int2* __restrict__ bkt) {
    __shared__ int cur[NBKT];
    int t = threadIdx.x, blk = blockIdx.x;
    for (int i = t; i < NBKT; i += 1024) cur[i] = base[i * PBLK + blk];
    __syncthreads();
    int beg = blk * EPB, end = beg + EPB;
    for (int e = beg + t; e < end; e += 1024) {
        int src = ei[e];
        int dst = ei[NE + e];
        float u = ea[e];
        int b = dst >> BKT_SHIFT;
        int p = atomicAdd(&cur[b], 1);
        bkt[p] = make_int2(src | ((dst & (BKT_NODES - 1)) << 17), __float_as_int(u));
    }
}

// ---------------- layer-1 projection: ab1 = (a, b-a); r1 = x@root1 + bias1 ----------------
__global__ __launch_bounds__(256) void proj1_kernel(const float* __restrict__ x,
                                                    const float* __restrict__ W1,
                                                    const float* __restrict__ root1,
                                                    const float* __restrict__ bias1,
                                                    float2* __restrict__ ab1,
                                                    float* __restrict__ r1) {
    __shared__ float w[2 * F_IN * HID];
    __shared__ float wr[F_IN * HID];
    __shared__ float bb[HID];
    for (int i = threadIdx.x; i < 2 * F_IN * HID; i += 256) w[i] = W1[i];
    for (int i = threadIdx.x; i < F_IN * HID; i += 256) wr[i] = root1[i];
    if (threadIdx.x < HID) bb[threadIdx.x] = bias1[threadIdx.x];
    __syncthreads();
    int n = blockIdx.x * 256 + threadIdx.x;
    if (n >= NN) return;
    float accA[HID], accB[HID], accR[HID];
#pragma unroll
    for (int o = 0; o < HID; ++o) { accA[o] = 0.f; accB[o] = 0.f; accR[o] = bb[o]; }
    const float* xr = x + (size_t)n * F_IN;
    for (int f = 0; f < F_IN; ++f) {
        float xv = xr[f];
        const float* w0 = &w[f * HID];
        const float* w1 = &w[F_IN * HID + f * HID];
        const float* w2 = &wr[f * HID];
#pragma unroll
        for (int o = 0; o < HID; ++o) {
            accA[o] = fmaf(xv, w0[o], accA[o]);
            accB[o] = fmaf(xv, w1[o], accB[o]);
            accR[o] = fmaf(xv, w2[o], accR[o]);
        }
    }
    float2* ar = ab1 + (size_t)n * HID;
    float* rr = r1 + (size_t)n * HID;
#pragma unroll
    for (int o = 0; o < HID; ++o) {
        ar[o] = make_float2(accA[o], accB[o] - accA[o]);
        rr[o] = accR[o];
    }
}

// ---- layer-1: sort bucket edges by local node in LDS, register-accumulate, ELU -> h ----
__global__ __launch_bounds__(512) void gather1_kernel(const int* __restrict__ bbase,
                                                      const int2* __restrict__ bkt,
                                                      const float2* __restrict__ ab1,
                                                      const float* __restrict__ r1,
                                                      float* __restrict__ h,
                                                      float* __restrict__ dinv) {
    __shared__ int2 sorted[CAP];            // 12 KB
    __shared__ int cnt[BKT_NODES], cur[BKT_NODES], segb[BKT_NODES + 1];
    __shared__ float accL[BKT_NODES * HID]; // legacy path only
    __shared__ float degsL[BKT_NODES];
    int t = threadIdx.x;
    int b = blockIdx.x;
    int beg = bbase[b], end = bbase[b + 1];
    int tot = end - beg;
    if (t < BKT_NODES) { cnt[t] = 0; cur[t] = 0; degsL[t] = 0.f; }
    __syncthreads();
    int nodeBase = b * BKT_NODES;

    if (tot <= CAP) {
        // ---- fast path ----
        for (int e = beg + t; e < end; e += 512)
            atomicAdd(&cnt[((unsigned)bkt[e].x) >> 17], 1);
        __syncthreads();
        if (t < BKT_NODES) {
            int v = cnt[t];
            int sc = v;
#pragma unroll
            for (int off = 1; off < 64; off <<= 1) {
                int o = __shfl_up(sc, off, 64);
                if (t >= off) sc += o;
            }
            segb[t] = sc - v;
            if (t == 63) segb[64] = sc;
        }
        __syncthreads();
        for (int e = beg + t; e < end; e += 512) {
            int2 pk = bkt[e];
            int loc = ((unsigned)pk.x) >> 17;
            int pos = segb[loc] + atomicAdd(&cur[loc], 1);
            sorted[pos] = pk;
        }
        __syncthreads();
        int j = t & (HID - 1);
        int g = t >> 4;                 // 32 groups, nodes 2g, 2g+1
        int s = segb[2 * g], mid = segb[2 * g + 1], e2 = segb[2 * g + 2];
        float a0 = 0.f, a1 = 0.f;
        int e = s;
        for (; e + 8 <= e2; e += 8) {
            float val[8]; int sel[8];
#pragma unroll
            for (int k = 0; k < 8; ++k) {
                int2 pk = sorted[e + k];
                float2 ab = ab1[(size_t)(pk.x & SRCM) * HID + j];
                val[k] = fmaf(__int_as_float(pk.y), ab.y, ab.x);
                sel[k] = (e + k) >= mid;
            }
#pragma unroll
            for (int k = 0; k < 8; ++k) {
                a0 += sel[k] ? 0.f : val[k];
                a1 += sel[k] ? val[k] : 0.f;
            }
        }
        for (; e < e2; ++e) {
            int2 pk = sorted[e];
            float2 ab = ab1[(size_t)(pk.x & SRCM) * HID + j];
            float val = fmaf(__int_as_float(pk.y), ab.y, ab.x);
            if (e >= mid) a1 += val; else a0 += val;
        }
        float d0 = 1.f / (float)max(mid - s, 1);
        float d1 = 1.f / (float)max(e2 - mid, 1);
        int n0 = nodeBase + 2 * g, n1 = n0 + 1;
        if (n0 < NN) {
            float v = a0 * d0 + r1[(size_t)n0 * HID + j];
            h[(size_t)n0 * HID + j] = v > 0.f ? v : expm1f(v);
            if (j == 0) dinv[n0] = d0;
        }
        if (n1 < NN) {
            float v = a1 * d1 + r1[(size_t)n1 * HID + j];
            h[(size_t)n1 * HID + j] = v > 0.f ? v : expm1f(v);
            if (j == 0) dinv[n1] = d1;
        }
    } else {
        // ---- legacy atomic path (bucket overflow; statistically never) ----
        for (int i = t; i < BKT_NODES * HID; i += 512) accL[i] = 0.f;
        __syncthreads();
        int j = t & (HID - 1);
        int g = t >> 4;
        for (int e = beg + g; e < end; e += 32) {
            int2 pk = bkt[e];
            float2 ab = ab1[(size_t)(pk.x & SRCM) * HID + j];
            atomicAdd(&accL[(pk.x >> 17) * HID + j], fmaf(__int_as_float(pk.y), ab.y, ab.x));
            if (j == 0) atomicAdd(&degsL[pk.x >> 17], 1.f);
        }
        __syncthreads();
        if (t < BKT_NODES) degsL[t] = 1.f / fmaxf(degsL[t], 1.f);
        __syncthreads();
#pragma unroll
        for (int it = 0; it < BKT_NODES * HID / 512; ++it) {
            int idx = it * 512 + t;
            int nl = idx >> 4, jj = idx & (HID - 1);
            int n = nodeBase + nl;
            if (n < NN) {
                float v = accL[idx] * degsL[nl] + r1[(size_t)n * HID + jj];
                h[(size_t)n * HID + jj] = v > 0.f ? v : expm1f(v);
            }
        }
        if (t < BKT_NODES && nodeBase + t < NN) dinv[nodeBase + t] = degsL[t];
    }
}

// ---- layer-2: sorted register-accumulate S0=Σh, S1=Σu·h; project + root + log_softmax ----
__global__ __launch_bounds__(512) void gather2_kernel(const int* __restrict__ bbase,
                                                      const int2* __restrict__ bkt,
                                                      const float* __restrict__ h,
                                                      const float* __restrict__ W2,
                                                      const float* __restrict__ root2,
                                                      const float* __restrict__ bias2,
                                                      const float* __restrict__ dinv,
                                                      float* __restrict__ out) {
    __shared__ int2 sorted[CAP];            // 12 KB
    __shared__ int cnt[BKT_NODES], cur[BKT_NODES], segb[BKT_NODES + 1];
    __shared__ float s0L[BKT_NODES * HID];  // 4 KB
    __shared__ float s1L[BKT_NODES * HID];  // 4 KB
    __shared__ float w20[HID * OUTF], w2d[HID * OUTF], wr[HID * OUTF];
    __shared__ float bb[OUTF];
    int t = threadIdx.x;
    for (int i = t; i < HID * OUTF; i += 512) {
        float a = W2[i];
        w20[i] = a;
        w2d[i] = W2[HID * OUTF + i] - a;
        wr[i] = root2[i];
    }
    if (t < OUTF) bb[t] = bias2[t];
    if (t < BKT_NODES) { cnt[t] = 0; cur[t] = 0; }
    int b = blockIdx.x;
    int beg = bbase[b], end = bbase[b + 1];
    int tot = end - beg;
    __syncthreads();

    if (tot <= CAP) {
        for (int e = beg + t; e < end; e += 512)
            atomicAdd(&cnt[((unsigned)bkt[e].x) >> 17], 1);
        __syncthreads();
        if (t < BKT_NODES) {
            int v = cnt[t];
            int sc = v;
#pragma unroll
            for (int off = 1; off < 64; off <<= 1) {
                int o = __shfl_up(sc, off, 64);
                if (t >= off) sc += o;
            }
            segb[t] = sc - v;
            if (t == 63) segb[64] = sc;
        }
        __syncthreads();
        for (int e = beg + t; e < end; e += 512) {
            int2 pk = bkt[e];
            int loc = ((unsigned)pk.x) >> 17;
            int pos = segb[loc] + atomicAdd(&cur[loc], 1);
            sorted[pos] = pk;
        }
        __syncthreads();
        int j = t & (HID - 1);
        int g = t >> 4;
        int s = segb[2 * g], mid = segb[2 * g + 1], e2 = segb[2 * g + 2];
        float s00 = 0.f, s10 = 0.f, s01 = 0.f, s11 = 0.f;
        int e = s;
        for (; e + 8 <= e2; e += 8) {
            float hv[8], uv[8]; int sel[8];
#pragma unroll
            for (int k = 0; k < 8; ++k) {
                int2 pk = sorted[e + k];
                hv[k] = h[(size_t)(pk.x & SRCM) * HID + j];
                uv[k] = __int_as_float(pk.y);
                sel[k] = (e + k) >= mid;
            }
#pragma unroll
            for (int k = 0; k < 8; ++k) {
                float uh = uv[k] * hv[k];
                s00 += sel[k] ? 0.f : hv[k];
                s10 += sel[k] ? 0.f : uh;
                s01 += sel[k] ? hv[k] : 0.f;
                s11 += sel[k] ? uh : 0.f;
            }
        }
        for (; e < e2; ++e) {
            int2 pk = sorted[e];
            float hvv = h[(size_t)(pk.x & SRCM) * HID + j];
            float uh = __int_as_float(pk.y) * hvv;
            if (e >= mid) { s01 += hvv; s11 += uh; }
            else          { s00 += hvv; s10 += uh; }
        }
        s0L[(2 * g) * HID + j] = s00;
        s1L[(2 * g) * HID + j] = s10;
        s0L[(2 * g + 1) * HID + j] = s01;
        s1L[(2 * g + 1) * HID + j] = s11;
        __syncthreads();
    } else {
        for (int i = t; i < BKT_NODES * HID; i += 512) { s0L[i] = 0.f; s1L[i] = 0.f; }
        __syncthreads();
        int j = t & (HID - 1);
        int g = t >> 4;
        for (int e = beg + g; e < end; e += 32) {
            int2 pk = bkt[e];
            float hvv = h[(size_t)(pk.x & SRCM) * HID + j];
            int l = pk.x >> 17;
            atomicAdd(&s0L[l * HID + j], hvv);
            atomicAdd(&s1L[l * HID + j], __int_as_float(pk.y) * hvv);
        }
        __syncthreads();
    }

    int nodeBase = b * BKT_NODES;
#pragma unroll
    for (int it = 0; it < BKT_NODES * OUTF / 512; ++it) {  // 4
        int idx = it * 512 + t;
        int nl = idx >> 5, jj = idx & (OUTF - 1);
        int n = nodeBase + nl;
        float v = 0.f;
        if (n < NN) {
            float msum = 0.f;
            const float* S0 = &s0L[nl * HID];
            const float* S1 = &s1L[nl * HID];
#pragma unroll
            for (int f = 0; f < HID; ++f)
                msum += S0[f] * w20[f * OUTF + jj] + S1[f] * w2d[f * OUTF + jj];
            v = msum * dinv[n] + bb[jj];
            const float* hr = h + (size_t)n * HID;
#pragma unroll
            for (int f = 0; f < HID; ++f) v = fmaf(hr[f], wr[f * OUTF + jj], v);
        }
        float m = v;
#pragma unroll
        for (int mask = 16; mask >= 1; mask >>= 1) m = fmaxf(m, __shfl_xor(m, mask));
        float ex = expf(v - m);
        float sm = ex;
#pragma unroll
        for (int mask = 16; mask >= 1; mask >>= 1) sm += __shfl_xor(sm, mask);
        if (n < NN) out[(size_t)n * OUTF + jj] = v - m - logf(sm);
    }
}

extern "C" void kernel_launch(void* const* d_in, const int* in_sizes, int n_in,
                              void* d_out, int out_size, void* d_ws, size_t ws_size,
                              hipStream_t stream) {
    const float* x     = (const float*)d_in[0];
    const int*   ei    = (const int*)d_in[1];
    const float* ea    = (const float*)d_in[3];
    const float* W1    = (const float*)d_in[4];
    const float* root1 = (const float*)d_in[5];
    const float* bias1 = (const float*)d_in[6];
    const float* W2    = (const float*)d_in[7];
    const float* root2 = (const float*)d_in[8];
    const float* bias2 = (const float*)d_in[9];
    float* out = (float*)d_out;
    float* ws  = (float*)d_ws;

    const size_t N = NN;
    int*    hist   = (int*)(ws);                      // 100032
    int*    base   = (int*)(ws + 100032);             // 100032
    int*    bbase  = (int*)(ws + 200064);             // 1564
    int*    bktsum = (int*)(ws + 201664);             // 1563
    float*  dinv   = ws + 203300;                     // 100000
    float*  h      = ws + 303300;                     // 16N
    int2*   bkt    = (int2*)(ws + 303300 + 16 * N);   // 32N floats
    float2* ab1    = (float2*)(ws + 303300 + 48 * N); // 32N floats
    float*  r1     = ws + 303300 + 80 * N;            // 16N floats

    int nbN = (NN + 255) / 256;
    histA_kernel<<<PBLK, 1024, 0, stream>>>(ei, hist);
    scanS1_kernel<<<(NBKT + 3) / 4, 256, 0, stream>>>(hist, base, bktsum);
    scanS2_kernel<<<1, 1024, 0, stream>>>(bktsum, bbase);
    scanS3_kernel<<<(M_HIST + 255) / 256, 256, 0, stream>>>(base, bbase);
    scatterC_kernel<<<PBLK, 1024, 0, stream>>>(ei, ea, base, bkt);

    proj1_kernel<<<nbN, 256, 0, stream>>>(x, W1, root1, bias1, ab1, r1);
    gather1_kernel<<<NBKT, 512, 0, stream>>>(bbase, bkt, ab1, r1, h, dinv);
    gather2_kernel<<<NBKT, 512, 0, stream>>>(bbase, bkt, h, W2, root2, bias2, dinv, out);
}

// Round 8
// 128.817 us; speedup vs baseline: 11.1060x; 1.3875x over previous
//
#include <hip/hip_runtime.h>
#include <math.h>

#define NN 100000
#define NE 1600000
#define F_IN 64
#define HID 16
#define OUTF 32
#define BKT_SHIFT 6
#define BKT_NODES 64
#define NBKT 1563               // ceil(NN/64)
#define SRCM 0x1FFFF
#define CAP_REG 2048            // fixed region per bucket (mean 1024, sd 32 -> never hit)
#define CAP_LDS 1536            // fast-path LDS sort capacity
#define PBLK2 256
#define EPB2 (NE / PBLK2)       // 6250
#define OVF_MAX 4096

__device__ __forceinline__ unsigned bf16r(float f) {   // round-to-nearest-even bf16 (finite)
    unsigned u = __float_as_uint(f);
    return (u + 0x7FFFu + ((u >> 16) & 1u)) >> 16;
}
__device__ __forceinline__ float bfa(unsigned p) { return __uint_as_float(p << 16); }          // low half
__device__ __forceinline__ float bfd(unsigned p) { return __uint_as_float(p & 0xFFFF0000u); }  // high half

// ---- fused partition: LDS hist -> global region claim -> LDS-rank scatter ----
__global__ __launch_bounds__(1024) void partF_kernel(const int* __restrict__ ei,
                                                     const float* __restrict__ ea,
                                                     int* __restrict__ gcur,
                                                     int* __restrict__ novf,
                                                     int4* __restrict__ ovf,
                                                     int2* __restrict__ bkt) {
    __shared__ int hcnt[NBKT];
    __shared__ int hbase[NBKT];
    int t = threadIdx.x, blk = blockIdx.x;
    for (int i = t; i < NBKT; i += 1024) hcnt[i] = 0;
    __syncthreads();
    int beg = blk * EPB2, end = beg + EPB2;
    for (int e = beg + t; e < end; e += 1024)
        atomicAdd(&hcnt[ei[NE + e] >> BKT_SHIFT], 1);
    __syncthreads();
    for (int i = t; i < NBKT; i += 1024) {
        int c = hcnt[i];
        hbase[i] = c ? atomicAdd(&gcur[i], c) : 0;
        hcnt[i] = 0;  // reuse as local rank cursor
    }
    __syncthreads();
    for (int e = beg + t; e < end; e += 1024) {
        int src = ei[e];
        int dst = ei[NE + e];
        float u = ea[e];
        int b = dst >> BKT_SHIFT;
        int r = atomicAdd(&hcnt[b], 1);
        int pos = hbase[b] + r;
        int pay = src | ((dst & (BKT_NODES - 1)) << 17);
        if (pos < CAP_REG) {
            bkt[(size_t)b * CAP_REG + pos] = make_int2(pay, __float_as_int(u));
        } else {
            int o = atomicAdd(novf, 1);
            if (o < OVF_MAX) ovf[o] = make_int4(dst, src, __float_as_int(u), 0);
        }
    }
}

// ---- layer-1 projection: ab1p[n][j] = pack_bf16(a, b-a); r1 = x@root1 + bias1 (fp32) ----
__global__ __launch_bounds__(256) void proj1_kernel(const float* __restrict__ x,
                                                    const float* __restrict__ W1,
                                                    const float* __restrict__ root1,
                                                    const float* __restrict__ bias1,
                                                    unsigned* __restrict__ ab1p,
                                                    float* __restrict__ r1) {
    __shared__ float w[2 * F_IN * HID];
    __shared__ float wr[F_IN * HID];
    __shared__ float bb[HID];
    for (int i = threadIdx.x; i < 2 * F_IN * HID; i += 256) w[i] = W1[i];
    for (int i = threadIdx.x; i < F_IN * HID; i += 256) wr[i] = root1[i];
    if (threadIdx.x < HID) bb[threadIdx.x] = bias1[threadIdx.x];
    __syncthreads();
    int n = blockIdx.x * 256 + threadIdx.x;
    if (n >= NN) return;
    float accA[HID], accB[HID], accR[HID];
#pragma unroll
    for (int o = 0; o < HID; ++o) { accA[o] = 0.f; accB[o] = 0.f; accR[o] = bb[o]; }
    const float* xr = x + (size_t)n * F_IN;
    for (int f = 0; f < F_IN; ++f) {
        float xv = xr[f];
        const float* w0 = &w[f * HID];
        const float* w1 = &w[F_IN * HID + f * HID];
        const float* w2 = &wr[f * HID];
#pragma unroll
        for (int o = 0; o < HID; ++o) {
            accA[o] = fmaf(xv, w0[o], accA[o]);
            accB[o] = fmaf(xv, w1[o], accB[o]);
            accR[o] = fmaf(xv, w2[o], accR[o]);
        }
    }
    unsigned* ar = ab1p + (size_t)n * HID;
    float* rr = r1 + (size_t)n * HID;
#pragma unroll
    for (int o = 0; o < HID; ++o) {
        ar[o] = bf16r(accA[o]) | (bf16r(accB[o] - accA[o]) << 16);
        rr[o] = accR[o];
    }
}

// ---- layer-1: LDS counting-sort + register accumulate + mean + root + ELU -> h16 ----
__global__ __launch_bounds__(512) void gather1_kernel(const int* __restrict__ gcur,
                                                      const int* __restrict__ novf,
                                                      const int4* __restrict__ ovf,
                                                      const int2* __restrict__ bkt,
                                                      const unsigned* __restrict__ ab1p,
                                                      const float* __restrict__ r1,
                                                      unsigned short* __restrict__ h16,
                                                      float* __restrict__ dinv) {
    __shared__ int2 sorted[CAP_LDS];        // 12 KB
    __shared__ int cnt[BKT_NODES], cur[BKT_NODES], segb[BKT_NODES + 1];
    __shared__ float accL[BKT_NODES * HID]; // legacy path only
    __shared__ float degsL[BKT_NODES];
    int t = threadIdx.x;
    int b = blockIdx.x;
    int tot = gcur[b];
    int beg = b * CAP_REG;
    if (t < BKT_NODES) { cnt[t] = 0; cur[t] = 0; degsL[t] = 0.f; }
    __syncthreads();
    int nodeBase = b * BKT_NODES;

    if (tot <= CAP_LDS) {
        int end = beg + tot;
        for (int e = beg + t; e < end; e += 512)
            atomicAdd(&cnt[((unsigned)bkt[e].x) >> 17], 1);
        __syncthreads();
        if (t < BKT_NODES) {
            int v = cnt[t];
            int sc = v;
#pragma unroll
            for (int off = 1; off < 64; off <<= 1) {
                int o = __shfl_up(sc, off, 64);
                if (t >= off) sc += o;
            }
            segb[t] = sc - v;
            if (t == 63) segb[64] = sc;
        }
        __syncthreads();
        for (int e = beg + t; e < end; e += 512) {
            int2 pk = bkt[e];
            int loc = ((unsigned)pk.x) >> 17;
            int pos = segb[loc] + atomicAdd(&cur[loc], 1);
            sorted[pos] = pk;
        }
        __syncthreads();
        int j = t & (HID - 1);
        int g = t >> 4;                 // 32 groups, nodes 2g, 2g+1
        int s = segb[2 * g], mid = segb[2 * g + 1], e2 = segb[2 * g + 2];
        float a0 = 0.f, a1 = 0.f;
        int e = s;
        for (; e + 8 <= e2; e += 8) {
            float val[8]; int sel[8];
#pragma unroll
            for (int k = 0; k < 8; ++k) {
                int2 pk = sorted[e + k];
                unsigned p = ab1p[(size_t)(pk.x & SRCM) * HID + j];
                val[k] = fmaf(__int_as_float(pk.y), bfd(p), bfa(p));
                sel[k] = (e + k) >= mid;
            }
#pragma unroll
            for (int k = 0; k < 8; ++k) {
                a0 += sel[k] ? 0.f : val[k];
                a1 += sel[k] ? val[k] : 0.f;
            }
        }
        for (; e < e2; ++e) {
            int2 pk = sorted[e];
            unsigned p = ab1p[(size_t)(pk.x & SRCM) * HID + j];
            float val = fmaf(__int_as_float(pk.y), bfd(p), bfa(p));
            if (e >= mid) a1 += val; else a0 += val;
        }
        float d0 = 1.f / (float)max(mid - s, 1);
        float d1 = 1.f / (float)max(e2 - mid, 1);
        int n0 = nodeBase + 2 * g, n1 = n0 + 1;
        if (n0 < NN) {
            float v = a0 * d0 + r1[(size_t)n0 * HID + j];
            h16[(size_t)n0 * HID + j] = (unsigned short)bf16r(v > 0.f ? v : expm1f(v));
            if (j == 0) dinv[n0] = d0;
        }
        if (n1 < NN) {
            float v = a1 * d1 + r1[(size_t)n1 * HID + j];
            h16[(size_t)n1 * HID + j] = (unsigned short)bf16r(v > 0.f ? v : expm1f(v));
            if (j == 0) dinv[n1] = d1;
        }
    } else {
        // ---- legacy atomic path (bucket overflow; statistically never) ----
        int inreg = min(tot, CAP_REG);
        int end = beg + inreg;
        for (int i = t; i < BKT_NODES * HID; i += 512) accL[i] = 0.f;
        __syncthreads();
        int j = t & (HID - 1);
        int g = t >> 4;
        for (int e = beg + g; e < end; e += 32) {
            int2 pk = bkt[e];
            unsigned p = ab1p[(size_t)(pk.x & SRCM) * HID + j];
            atomicAdd(&accL[(((unsigned)pk.x) >> 17) * HID + j],
                      fmaf(__int_as_float(pk.y), bfd(p), bfa(p)));
            if (j == 0) atomicAdd(&degsL[((unsigned)pk.x) >> 17], 1.f);
        }
        int ovn = min(novf[0], OVF_MAX);
        for (int o = 0; o < ovn; ++o) {
            int4 ent = ovf[o];
            int loc = ent.x - nodeBase;
            if (loc >= 0 && loc < BKT_NODES && g == 0) {
                unsigned p = ab1p[(size_t)ent.y * HID + j];
                atomicAdd(&accL[loc * HID + j], fmaf(__int_as_float(ent.z), bfd(p), bfa(p)));
                if (j == 0) atomicAdd(&degsL[loc], 1.f);
            }
        }
        __syncthreads();
        if (t < BKT_NODES) degsL[t] = 1.f / fmaxf(degsL[t], 1.f);
        __syncthreads();
#pragma unroll
        for (int it = 0; it < BKT_NODES * HID / 512; ++it) {
            int idx = it * 512 + t;
            int nl = idx >> 4, jj = idx & (HID - 1);
            int n = nodeBase + nl;
            if (n < NN) {
                float v = accL[idx] * degsL[nl] + r1[(size_t)n * HID + jj];
                h16[(size_t)n * HID + jj] = (unsigned short)bf16r(v > 0.f ? v : expm1f(v));
            }
        }
        if (t < BKT_NODES && nodeBase + t < NN) dinv[nodeBase + t] = degsL[t];
    }
}

// ---- layer-2: sorted register-accumulate S0=Σh, S1=Σu·h; project + root + log_softmax ----
__global__ __launch_bounds__(512) void gather2_kernel(const int* __restrict__ gcur,
                                                      const int* __restrict__ novf,
                                                      const int4* __restrict__ ovf,
                                                      const int2* __restrict__ bkt,
                                                      const unsigned short* __restrict__ h16,
                                                      const float* __restrict__ W2,
                                                      const float* __restrict__ root2,
                                                      const float* __restrict__ bias2,
                                                      const float* __restrict__ dinv,
                                                      float* __restrict__ out) {
    __shared__ int2 sorted[CAP_LDS];        // 12 KB
    __shared__ int cnt[BKT_NODES], cur[BKT_NODES], segb[BKT_NODES + 1];
    __shared__ float s0L[BKT_NODES * HID];  // 4 KB
    __shared__ float s1L[BKT_NODES * HID];  // 4 KB
    __shared__ float w20[HID * OUTF], w2d[HID * OUTF], wr[HID * OUTF];
    __shared__ float bb[OUTF];
    int t = threadIdx.x;
    for (int i = t; i < HID * OUTF; i += 512) {
        float a = W2[i];
        w20[i] = a;
        w2d[i] = W2[HID * OUTF + i] - a;
        wr[i] = root2[i];
    }
    if (t < OUTF) bb[t] = bias2[t];
    if (t < BKT_NODES) { cnt[t] = 0; cur[t] = 0; }
    int b = blockIdx.x;
    int tot = gcur[b];
    int beg = b * CAP_REG;
    int nodeBase = b * BKT_NODES;
    __syncthreads();

    if (tot <= CAP_LDS) {
        int end = beg + tot;
        for (int e = beg + t; e < end; e += 512)
            atomicAdd(&cnt[((unsigned)bkt[e].x) >> 17], 1);
        __syncthreads();
        if (t < BKT_NODES) {
            int v = cnt[t];
            int sc = v;
#pragma unroll
            for (int off = 1; off < 64; off <<= 1) {
                int o = __shfl_up(sc, off, 64);
                if (t >= off) sc += o;
            }
            segb[t] = sc - v;
            if (t == 63) segb[64] = sc;
        }
        __syncthreads();
        for (int e = beg + t; e < end; e += 512) {
            int2 pk = bkt[e];
            int loc = ((unsigned)pk.x) >> 17;
            int pos = segb[loc] + atomicAdd(&cur[loc], 1);
            sorted[pos] = pk;
        }
        __syncthreads();
        int j = t & (HID - 1);
        int g = t >> 4;
        int s = segb[2 * g], mid = segb[2 * g + 1], e2 = segb[2 * g + 2];
        float s00 = 0.f, s10 = 0.f, s01 = 0.f, s11 = 0.f;
        int e = s;
        for (; e + 8 <= e2; e += 8) {
            float hv[8], uv[8]; int sel[8];
#pragma unroll
            for (int k = 0; k < 8; ++k) {
                int2 pk = sorted[e + k];
                hv[k] = __uint_as_float(((unsigned)h16[(size_t)(pk.x & SRCM) * HID + j]) << 16);
                uv[k] = __int_as_float(pk.y);
                sel[k] = (e + k) >= mid;
            }
#pragma unroll
            for (int k = 0; k < 8; ++k) {
                float uh = uv[k] * hv[k];
                s00 += sel[k] ? 0.f : hv[k];
                s10 += sel[k] ? 0.f : uh;
                s01 += sel[k] ? hv[k] : 0.f;
                s11 += sel[k] ? uh : 0.f;
            }
        }
        for (; e < e2; ++e) {
            int2 pk = sorted[e];
            float hvv = __uint_as_float(((unsigned)h16[(size_t)(pk.x & SRCM) * HID + j]) << 16);
            float uh = __int_as_float(pk.y) * hvv;
            if (e >= mid) { s01 += hvv; s11 += uh; }
            else          { s00 += hvv; s10 += uh; }
        }
        s0L[(2 * g) * HID + j] = s00;
        s1L[(2 * g) * HID + j] = s10;
        s0L[(2 * g + 1) * HID + j] = s01;
        s1L[(2 * g + 1) * HID + j] = s11;
        __syncthreads();
    } else {
        int inreg = min(tot, CAP_REG);
        int end = beg + inreg;
        for (int i = t; i < BKT_NODES * HID; i += 512) { s0L[i] = 0.f; s1L[i] = 0.f; }
        __syncthreads();
        int j = t & (HID - 1);
        int g = t >> 4;
        for (int e = beg + g; e < end; e += 32) {
            int2 pk = bkt[e];
            float hvv = __uint_as_float(((unsigned)h16[(size_t)(pk.x & SRCM) * HID + j]) << 16);
            int l = ((unsigned)pk.x) >> 17;
            atomicAdd(&s0L[l * HID + j], hvv);
            atomicAdd(&s1L[l * HID + j], __int_as_float(pk.y) * hvv);
        }
        int ovn = min(novf[0], OVF_MAX);
        for (int o = 0; o < ovn; ++o) {
            int4 ent = ovf[o];
            int loc = ent.x - nodeBase;
            if (loc >= 0 && loc < BKT_NODES && g == 0) {
                float hvv = __uint_as_float(((unsigned)h16[(size_t)ent.y * HID + j]) << 16);
                atomicAdd(&s0L[loc * HID + j], hvv);
                atomicAdd(&s1L[loc * HID + j], __int_as_float(ent.z) * hvv);
            }
        }
        __syncthreads();
    }

#pragma unroll
    for (int it = 0; it < BKT_NODES * OUTF / 512; ++it) {  // 4
        int idx = it * 512 + t;
        int nl = idx >> 5, jj = idx & (OUTF - 1);
        int n = nodeBase + nl;
        float v = 0.f;
        if (n < NN) {
            float msum = 0.f;
            const float* S0 = &s0L[nl * HID];
            const float* S1 = &s1L[nl * HID];
#pragma unroll
            for (int f = 0; f < HID; ++f)
                msum += S0[f] * w20[f * OUTF + jj] + S1[f] * w2d[f * OUTF + jj];
            v = msum * dinv[n] + bb[jj];
            const unsigned short* hr = h16 + (size_t)n * HID;
#pragma unroll
            for (int f = 0; f < HID; ++f)
                v = fmaf(__uint_as_float(((unsigned)hr[f]) << 16), wr[f * OUTF + jj], v);
        }
        float m = v;
#pragma unroll
        for (int mask = 16; mask >= 1; mask >>= 1) m = fmaxf(m, __shfl_xor(m, mask));
        float ex = expf(v - m);
        float sm = ex;
#pragma unroll
        for (int mask = 16; mask >= 1; mask >>= 1) sm += __shfl_xor(sm, mask);
        if (n < NN) out[(size_t)n * OUTF + jj] = v - m - logf(sm);
    }
}

extern "C" void kernel_launch(void* const* d_in, const int* in_sizes, int n_in,
                              void* d_out, int out_size, void* d_ws, size_t ws_size,
                              hipStream_t stream) {
    const float* x     = (const float*)d_in[0];
    const int*   ei    = (const int*)d_in[1];
    const float* ea    = (const float*)d_in[3];
    const float* W1    = (const float*)d_in[4];
    const float* root1 = (const float*)d_in[5];
    const float* bias1 = (const float*)d_in[6];
    const float* W2    = (const float*)d_in[7];
    const float* root2 = (const float*)d_in[8];
    const float* bias2 = (const float*)d_in[9];
    float* out = (float*)d_out;
    float* ws  = (float*)d_ws;

    const size_t N = NN;
    // workspace (float units), total ~10.52M floats = 42.1 MB
    int*            gcur = (int*)(ws);                    // [0, 1563)
    int*            novf = (int*)(ws + 2000);             // 1
    int4*           ovf  = (int4*)(ws + 2048);            // OVF_MAX int4
    float*          dinv = ws + 20000;                    // 100000
    float*          r1   = ws + 120000;                   // 16N
    unsigned*       ab1p = (unsigned*)(ws + 120000 + 16 * N);   // 16N u32
    unsigned short* h16  = (unsigned short*)(ws + 120000 + 32 * N); // 16N u16 = 8N floats
    int2*           bkt  = (int2*)(ws + 120000 + 40 * N); // NBKT*CAP_REG int2 = 64.02N floats

    hipMemsetAsync(gcur, 0, 8448, stream);  // gcur + novf region

    int nbN = (NN + 255) / 256;
    partF_kernel<<<PBLK2, 1024, 0, stream>>>(ei, ea, gcur, novf, ovf, bkt);
    proj1_kernel<<<nbN, 256, 0, stream>>>(x, W1, root1, bias1, ab1p, r1);
    gather1_kernel<<<NBKT, 512, 0, stream>>>(gcur, novf, ovf, bkt, ab1p, r1, h16, dinv);
    gather2_kernel<<<NBKT, 512, 0, stream>>>(gcur, novf, ovf, bkt, h16, W2, root2, bias2, dinv, out);
}